// Round 1
// baseline (2525.978 us; speedup 1.0000x reference)
//
#include <hip/hip_runtime.h>

// ---------------------------------------------------------------------------
// SE3 conv layer, fp32 baseline.
//   out[n, 0:16]   = node_feat[n] @ (W_si/4)          (self-interaction)
//   out[n, 16:144] = 0
// then per edge e (src,dst):
//   h  = silu(radial @ W1/4)                (64)
//   mix[l,v] = sum_{k,u} h[k] * x[u] * W2[k,l,u,v] / (8*4)   (48)
//   msg: l0 -> mix0[v]*sh0 ; l1 -> mix1[v]*sh[1..3] ; l2 -> mix2[v]*sh[4..8]
//   atomicAdd into out[dst, :]
// ---------------------------------------------------------------------------

__global__ __launch_bounds__(256)
void si_init_kernel(const float* __restrict__ nf, const float* __restrict__ Wsi,
                    float* __restrict__ out, int N) {
    int t = blockIdx.x * blockDim.x + threadIdx.x;
    int total = N * 144;
    if (t >= total) return;
    int n = t / 144;
    int c = t - n * 144;
    float val = 0.0f;
    if (c < 16) {
        const float* xr = nf + n * 16;
        #pragma unroll
        for (int u = 0; u < 16; ++u)
            val = fmaf(xr[u], Wsi[u * 16 + c], val);
        val *= 0.25f;   // 1/sqrt(16)
    }
    out[t] = val;
}

__global__ __launch_bounds__(256)
void edge_kernel(const float* __restrict__ nf, const int* __restrict__ ei,
                 const float* __restrict__ sh, const float* __restrict__ radial,
                 const float* __restrict__ W1, const float* __restrict__ W2,
                 float* __restrict__ out, int E) {
    int e = blockIdx.x * blockDim.x + threadIdx.x;
    if (e >= E) return;
    int src = ei[e];
    int dst = ei[E + e];

    // per-edge inputs; fold all sqrt normalizations into r and x
    float r[16], x[16];
    #pragma unroll
    for (int u = 0; u < 16; ++u) r[u] = radial[e * 16 + u] * 0.25f;     // 1/sqrt(16) of W1
    #pragma unroll
    for (int u = 0; u < 16; ++u) x[u] = nf[src * 16 + u] * 0.03125f;    // 1/sqrt(64) * 1/sqrt(16)

    float acc[48];
    #pragma unroll
    for (int j = 0; j < 48; ++j) acc[j] = 0.0f;

    // k-loop: compute h[k] on the fly, contract with x[u] against W2[k,l,u,v]
    for (int k = 0; k < 64; ++k) {
        float z = 0.0f;
        #pragma unroll
        for (int u = 0; u < 16; ++u)
            z = fmaf(r[u], W1[u * 64 + k], z);          // wave-uniform -> scalar loads
        float hk = z / (1.0f + __expf(-z));             // silu

        const float* w2k = W2 + k * 768;
        #pragma unroll 4
        for (int u = 0; u < 16; ++u) {
            float p = hk * x[u];
            const float* w = w2k + u * 16;              // W2[k, l, u, v] = w[l*256 + v]
            #pragma unroll
            for (int l = 0; l < 3; ++l) {
                #pragma unroll
                for (int v = 0; v < 16; ++v)
                    acc[l * 16 + v] = fmaf(p, w[l * 256 + v], acc[l * 16 + v]);
            }
        }
    }

    // messages: outer product with SH degrees, scatter-add to destination row
    const float* she = sh + e * 9;
    float sh0 = she[0];
    float sh1_0 = she[1], sh1_1 = she[2], sh1_2 = she[3];
    float sh2_0 = she[4], sh2_1 = she[5], sh2_2 = she[6], sh2_3 = she[7], sh2_4 = she[8];

    float* orow = out + (long)dst * 144;
    #pragma unroll
    for (int v = 0; v < 16; ++v)
        atomicAdd(&orow[v], acc[v] * sh0);
    #pragma unroll
    for (int v = 0; v < 16; ++v) {
        float m = acc[16 + v];
        atomicAdd(&orow[16 + v * 3 + 0], m * sh1_0);
        atomicAdd(&orow[16 + v * 3 + 1], m * sh1_1);
        atomicAdd(&orow[16 + v * 3 + 2], m * sh1_2);
    }
    #pragma unroll
    for (int v = 0; v < 16; ++v) {
        float m = acc[32 + v];
        atomicAdd(&orow[64 + v * 5 + 0], m * sh2_0);
        atomicAdd(&orow[64 + v * 5 + 1], m * sh2_1);
        atomicAdd(&orow[64 + v * 5 + 2], m * sh2_2);
        atomicAdd(&orow[64 + v * 5 + 3], m * sh2_3);
        atomicAdd(&orow[64 + v * 5 + 4], m * sh2_4);
    }
}

extern "C" void kernel_launch(void* const* d_in, const int* in_sizes, int n_in,
                              void* d_out, int out_size, void* d_ws, size_t ws_size,
                              hipStream_t stream) {
    const float* nf     = (const float*)d_in[0];
    const int*   ei     = (const int*)  d_in[1];
    const float* sh     = (const float*)d_in[2];
    const float* radial = (const float*)d_in[3];
    const float* W1     = (const float*)d_in[4];
    const float* W2     = (const float*)d_in[5];
    const float* Wsi    = (const float*)d_in[6];
    float* out = (float*)d_out;

    const int N = in_sizes[0] / 16;
    const int E = in_sizes[1] / 2;

    // 1) init out with self-interaction (also zeros l>0 block; out is poisoned)
    {
        int total = N * 144;
        int blocks = (total + 255) / 256;
        hipLaunchKernelGGL(si_init_kernel, dim3(blocks), dim3(256), 0, stream,
                           nf, Wsi, out, N);
    }
    // 2) per-edge fused radial-MLP + tensor product + scatter
    {
        int blocks = (E + 255) / 256;
        hipLaunchKernelGGL(edge_kernel, dim3(blocks), dim3(256), 0, stream,
                           nf, ei, sh, radial, W1, W2, out, E);
    }
}

// Round 2
// 477.259 us; speedup vs baseline: 5.2927x; 5.2927x over previous
//
#include <hip/hip_runtime.h>

// ---------------------------------------------------------------------------
// SE3 conv layer, atomic-free scatter via device-built CSR.
//   A) counts[dst+1]++                      (histogram)
//   B) inclusive scan -> exclusive offsets  (single block)
//   C) bucket edge ids by dst               (scatter)
//   D) per-edge: radial MLP + W2 contraction -> mix[e,48]  (compute-bound)
//   E) per-node wave: sum_{e in bucket} mix[e]*sh[e] + self-interaction
// ws layout: [ mix: E*48 f32 | offsets: N+1 i32 | cursor: N i32 | eord: E i32 ]
// Fallback to the R1 atomic path if ws_size is too small.
// ---------------------------------------------------------------------------

__global__ __launch_bounds__(256)
void hist_kernel(const int* __restrict__ ei, int* __restrict__ counts, int E) {
    int e = blockIdx.x * blockDim.x + threadIdx.x;
    if (e < E) atomicAdd(&counts[ei[E + e] + 1], 1);
}

__global__ __launch_bounds__(1024)
void scan_kernel(int* __restrict__ data, int n) {
    __shared__ int wsum[16];
    __shared__ int carry_s;
    int tid = threadIdx.x, lane = tid & 63, wid = tid >> 6;
    if (tid == 0) carry_s = 0;
    __syncthreads();
    for (int base = 0; base < n; base += 1024) {
        int i = base + tid;
        int v = (i < n) ? data[i] : 0;
        #pragma unroll
        for (int off = 1; off < 64; off <<= 1) {
            int t = __shfl_up(v, off, 64);
            if (lane >= off) v += t;
        }
        if (lane == 63) wsum[wid] = v;
        __syncthreads();
        if (wid == 0 && lane < 16) {
            int w = wsum[lane];
            #pragma unroll
            for (int off = 1; off < 16; off <<= 1) {
                int t = __shfl_up(w, off, 16);
                if (lane >= off) w += t;
            }
            wsum[lane] = w;
        }
        __syncthreads();
        int add = carry_s + (wid > 0 ? wsum[wid - 1] : 0);
        if (i < n) data[i] = v + add;
        __syncthreads();
        if (tid == 0) carry_s += wsum[15];
        __syncthreads();
    }
}

__global__ __launch_bounds__(256)
void scatter_kernel(const int* __restrict__ ei, const int* __restrict__ offs,
                    int* __restrict__ cursor, int* __restrict__ eord, int E) {
    int e = blockIdx.x * blockDim.x + threadIdx.x;
    if (e >= E) return;
    int dst = ei[E + e];
    int pos = offs[dst] + atomicAdd(&cursor[dst], 1);
    eord[pos] = e;
}

__global__ __launch_bounds__(256)
void edge_compute_kernel(const float* __restrict__ nf, const int* __restrict__ ei,
                         const float* __restrict__ radial,
                         const float* __restrict__ W1, const float* __restrict__ W2,
                         float* __restrict__ mix, int E) {
    int e = blockIdx.x * blockDim.x + threadIdx.x;
    if (e >= E) return;
    int src = ei[e];

    float r[16], x[16];
    #pragma unroll
    for (int u = 0; u < 16; ++u) r[u] = radial[e * 16 + u] * 0.25f;   // 1/sqrt(16)
    #pragma unroll
    for (int u = 0; u < 16; ++u) x[u] = nf[src * 16 + u] * 0.03125f;  // 1/sqrt(64)/sqrt(16)

    float acc[48];
    #pragma unroll
    for (int j = 0; j < 48; ++j) acc[j] = 0.0f;

    for (int k = 0; k < 64; ++k) {
        float z = 0.0f;
        #pragma unroll
        for (int u = 0; u < 16; ++u)
            z = fmaf(r[u], W1[u * 64 + k], z);        // wave-uniform -> s_load
        float hk = z / (1.0f + __expf(-z));           // silu

        const float* w2k = W2 + k * 768;              // W2[k, l*256 + u*16 + v]
        #pragma unroll 4
        for (int u = 0; u < 16; ++u) {
            float p = hk * x[u];
            const float* w = w2k + u * 16;
            #pragma unroll
            for (int l = 0; l < 3; ++l) {
                #pragma unroll
                for (int v = 0; v < 16; ++v)
                    acc[l * 16 + v] = fmaf(p, w[l * 256 + v], acc[l * 16 + v]);
            }
        }
    }

    float4* m4 = (float4*)(mix + (size_t)e * 48);
    #pragma unroll
    for (int j = 0; j < 12; ++j)
        m4[j] = make_float4(acc[4 * j], acc[4 * j + 1], acc[4 * j + 2], acc[4 * j + 3]);
}

__global__ __launch_bounds__(256)
void gather_kernel(const float* __restrict__ mix, const float* __restrict__ sh,
                   const int* __restrict__ eord, const int* __restrict__ offs,
                   const float* __restrict__ nf, const float* __restrict__ Wsi,
                   float* __restrict__ out, int N) {
    int node = blockIdx.x * 4 + (threadIdx.x >> 6);
    if (node >= N) return;
    int lane = threadIdx.x & 63;

    // channel c -> (mix index, sh index); lane owns c, c+64, (c+128 if lane<16)
    auto chmap = [](int c, int& mi, int& si) {
        if (c < 16)      { mi = c;                si = 0; }
        else if (c < 64) { int t = c - 16; mi = 16 + t / 3; si = 1 + t % 3; }
        else             { int t = c - 64; mi = 32 + t / 5; si = 4 + t % 5; }
    };
    int mi0, si0, mi1, si1, mi2 = 0, si2 = 0;
    chmap(lane, mi0, si0);
    chmap(lane + 64, mi1, si1);
    if (lane < 16) chmap(lane + 128, mi2, si2);

    float acc0 = 0.0f, acc1 = 0.0f, acc2 = 0.0f;
    int off = offs[node], end = offs[node + 1];
    for (int i = off; i < end; ++i) {
        int e = eord[i];
        const float* m = mix + (size_t)e * 48;
        const float* s = sh + (size_t)e * 9;
        acc0 = fmaf(m[mi0], s[si0], acc0);
        acc1 = fmaf(m[mi1], s[si1], acc1);
        if (lane < 16) acc2 = fmaf(m[mi2], s[si2], acc2);
    }

    if (lane < 16) {   // self-interaction, 0e->0e only
        const float* xr = nf + (size_t)node * 16;
        float si = 0.0f;
        #pragma unroll
        for (int u = 0; u < 16; ++u)
            si = fmaf(xr[u], Wsi[u * 16 + lane], si);
        acc0 = fmaf(si, 0.25f, acc0);
    }

    float* orow = out + (size_t)node * 144;
    orow[lane] = acc0;
    orow[lane + 64] = acc1;
    if (lane < 16) orow[lane + 128] = acc2;
}

// ------------------------- fallback (R1 atomic path) -----------------------

__global__ __launch_bounds__(256)
void si_init_kernel(const float* __restrict__ nf, const float* __restrict__ Wsi,
                    float* __restrict__ out, int N) {
    int t = blockIdx.x * blockDim.x + threadIdx.x;
    int total = N * 144;
    if (t >= total) return;
    int n = t / 144;
    int c = t - n * 144;
    float val = 0.0f;
    if (c < 16) {
        const float* xr = nf + n * 16;
        #pragma unroll
        for (int u = 0; u < 16; ++u)
            val = fmaf(xr[u], Wsi[u * 16 + c], val);
        val *= 0.25f;
    }
    out[t] = val;
}

__global__ __launch_bounds__(256)
void edge_kernel_atomic(const float* __restrict__ nf, const int* __restrict__ ei,
                        const float* __restrict__ sh, const float* __restrict__ radial,
                        const float* __restrict__ W1, const float* __restrict__ W2,
                        float* __restrict__ out, int E) {
    int e = blockIdx.x * blockDim.x + threadIdx.x;
    if (e >= E) return;
    int src = ei[e];
    int dst = ei[E + e];
    float r[16], x[16];
    #pragma unroll
    for (int u = 0; u < 16; ++u) r[u] = radial[e * 16 + u] * 0.25f;
    #pragma unroll
    for (int u = 0; u < 16; ++u) x[u] = nf[src * 16 + u] * 0.03125f;
    float acc[48];
    #pragma unroll
    for (int j = 0; j < 48; ++j) acc[j] = 0.0f;
    for (int k = 0; k < 64; ++k) {
        float z = 0.0f;
        #pragma unroll
        for (int u = 0; u < 16; ++u) z = fmaf(r[u], W1[u * 64 + k], z);
        float hk = z / (1.0f + __expf(-z));
        const float* w2k = W2 + k * 768;
        #pragma unroll 4
        for (int u = 0; u < 16; ++u) {
            float p = hk * x[u];
            const float* w = w2k + u * 16;
            #pragma unroll
            for (int l = 0; l < 3; ++l)
                #pragma unroll
                for (int v = 0; v < 16; ++v)
                    acc[l * 16 + v] = fmaf(p, w[l * 256 + v], acc[l * 16 + v]);
        }
    }
    const float* she = sh + e * 9;
    float* orow = out + (long)dst * 144;
    #pragma unroll
    for (int v = 0; v < 16; ++v) atomicAdd(&orow[v], acc[v] * she[0]);
    #pragma unroll
    for (int v = 0; v < 16; ++v)
        for (int m = 0; m < 3; ++m)
            atomicAdd(&orow[16 + v * 3 + m], acc[16 + v] * she[1 + m]);
    #pragma unroll
    for (int v = 0; v < 16; ++v)
        for (int m = 0; m < 5; ++m)
            atomicAdd(&orow[64 + v * 5 + m], acc[32 + v] * she[4 + m]);
}

// ---------------------------------------------------------------------------

extern "C" void kernel_launch(void* const* d_in, const int* in_sizes, int n_in,
                              void* d_out, int out_size, void* d_ws, size_t ws_size,
                              hipStream_t stream) {
    const float* nf     = (const float*)d_in[0];
    const int*   ei     = (const int*)  d_in[1];
    const float* sh     = (const float*)d_in[2];
    const float* radial = (const float*)d_in[3];
    const float* W1     = (const float*)d_in[4];
    const float* W2     = (const float*)d_in[5];
    const float* Wsi    = (const float*)d_in[6];
    float* out = (float*)d_out;

    const int N = in_sizes[0] / 16;
    const int E = in_sizes[1] / 2;

    // ws layout
    size_t mix_bytes  = (size_t)E * 48 * sizeof(float);
    size_t offs_bytes = (size_t)(N + 1) * sizeof(int);
    size_t curs_bytes = (size_t)N * sizeof(int);
    size_t eord_bytes = (size_t)E * sizeof(int);
    size_t need = mix_bytes + offs_bytes + curs_bytes + eord_bytes;

    if (ws_size < need) {
        // fallback: atomic scatter path
        int total = N * 144;
        hipLaunchKernelGGL(si_init_kernel, dim3((total + 255) / 256), dim3(256), 0, stream,
                           nf, Wsi, out, N);
        hipLaunchKernelGGL(edge_kernel_atomic, dim3((E + 255) / 256), dim3(256), 0, stream,
                           nf, ei, sh, radial, W1, W2, out, E);
        return;
    }

    float* mix   = (float*)d_ws;
    int*   offs  = (int*)((char*)d_ws + mix_bytes);
    int*   curs  = (int*)((char*)d_ws + mix_bytes + offs_bytes);
    int*   eord  = (int*)((char*)d_ws + mix_bytes + offs_bytes + curs_bytes);

    // zero counts + cursor (adjacent)
    hipMemsetAsync(offs, 0, offs_bytes + curs_bytes, stream);

    int eb = (E + 255) / 256;
    hipLaunchKernelGGL(hist_kernel, dim3(eb), dim3(256), 0, stream, ei, offs, E);
    hipLaunchKernelGGL(scan_kernel, dim3(1), dim3(1024), 0, stream, offs, N + 1);
    hipLaunchKernelGGL(scatter_kernel, dim3(eb), dim3(256), 0, stream, ei, offs, curs, eord, E);
    hipLaunchKernelGGL(edge_compute_kernel, dim3(eb), dim3(256), 0, stream,
                       nf, ei, radial, W1, W2, mix, E);
    hipLaunchKernelGGL(gather_kernel, dim3((N + 3) / 4), dim3(256), 0, stream,
                       mix, sh, eord, offs, nf, Wsi, out, N);
}

// Round 3
// 207.403 us; speedup vs baseline: 12.1791x; 2.3011x over previous
//
#include <hip/hip_runtime.h>

// ---------------------------------------------------------------------------
// SE3 conv layer. CSR-built scatter (no f32 atomics) + MFMA edge compute.
//   mix[e, lv] = sum_{ku} y[e,ku] * W2r[ku, lv],  y[e,k*16+u] = h[e,k]*x[e,u]
//   h = silu(radial @ W1/4);  W2r pre-packed as per-lane bf16 B-fragments.
// ws: [ mix E*48 f32 | offs N+1 i32 | curs N i32 | eord E i32 | (align) Bfrag 96KB ]
// ---------------------------------------------------------------------------

typedef short bf16x8 __attribute__((ext_vector_type(8)));
typedef float f32x4 __attribute__((ext_vector_type(4)));

union AFrag { unsigned int u[4]; bf16x8 v; };

__device__ inline unsigned int cvt_pk_bf16(float lo, float hi) {
    unsigned int r;
    asm("v_cvt_pk_bf16_f32 %0, %1, %2" : "=v"(r) : "v"(lo), "v"(hi));
    return r;
}

// ---------------------------- CSR build ------------------------------------

__global__ __launch_bounds__(256)
void hist_kernel(const int* __restrict__ ei, int* __restrict__ counts, int E) {
    int e = blockIdx.x * blockDim.x + threadIdx.x;
    if (e < E) atomicAdd(&counts[ei[E + e] + 1], 1);
}

__global__ __launch_bounds__(1024)
void scan_kernel(int* __restrict__ data, int n) {
    __shared__ int wsum[16];
    __shared__ int carry_s;
    int tid = threadIdx.x, lane = tid & 63, wid = tid >> 6;
    if (tid == 0) carry_s = 0;
    __syncthreads();
    for (int base = 0; base < n; base += 1024) {
        int i = base + tid;
        int v = (i < n) ? data[i] : 0;
        #pragma unroll
        for (int off = 1; off < 64; off <<= 1) {
            int t = __shfl_up(v, off, 64);
            if (lane >= off) v += t;
        }
        if (lane == 63) wsum[wid] = v;
        __syncthreads();
        if (wid == 0 && lane < 16) {
            int w = wsum[lane];
            #pragma unroll
            for (int off = 1; off < 16; off <<= 1) {
                int t = __shfl_up(w, off, 16);
                if (lane >= off) w += t;
            }
            wsum[lane] = w;
        }
        __syncthreads();
        int add = carry_s + (wid > 0 ? wsum[wid - 1] : 0);
        if (i < n) data[i] = v + add;
        __syncthreads();
        if (tid == 0) carry_s += wsum[15];
        __syncthreads();
    }
}

__global__ __launch_bounds__(256)
void scatter_kernel(const int* __restrict__ ei, const int* __restrict__ offs,
                    int* __restrict__ cursor, int* __restrict__ eord, int E) {
    int e = blockIdx.x * blockDim.x + threadIdx.x;
    if (e >= E) return;
    int dst = ei[E + e];
    int pos = offs[dst] + atomicAdd(&cursor[dst], 1);
    eord[pos] = e;
}

// ------------------------- B-fragment pre-pack -----------------------------
// Bfrag[f][lane][j], f = ks*3+nt (ks 0..31, nt 0..2), 8 bf16 per lane.
// element = W2[k][l*256+u*16+v] / 32, ku = ks*32 + (lane>>4)*8 + j,
// k=ku>>4, u=ku&15, n = nt*16 + (lane&15), l=n>>4, v=n&15.

__global__ __launch_bounds__(256)
void bfrag_prep_kernel(const float* __restrict__ W2, unsigned short* __restrict__ bfrag) {
    int t = blockIdx.x * 256 + threadIdx.x;
    if (t >= 96 * 512) return;
    int f = t >> 9;
    int rr = t & 511;
    int lane = rr >> 3, j = rr & 7;
    int ks = f / 3, nt = f - 3 * ks;
    int q = lane >> 4, c = lane & 15;
    int ku = ks * 32 + q * 8 + j;
    int k = ku >> 4, u = ku & 15;
    int n = nt * 16 + c;
    int l = n >> 4, v = n & 15;
    float val = W2[(size_t)k * 768 + l * 256 + u * 16 + v] * 0.03125f;
    unsigned int bits = __float_as_uint(val);
    unsigned int rnd = ((bits >> 16) & 1u) + 0x7fffu;   // RNE
    bfrag[t] = (unsigned short)((bits + rnd) >> 16);
}

// --------------------------- MFMA edge kernel ------------------------------
// block = 256 threads = 4 waves; each wave owns 64 edges (4 M-tiles of 16).

__global__ __launch_bounds__(256)
void edge_mfma_kernel(const float* __restrict__ nf, const int* __restrict__ ei,
                      const float* __restrict__ radial, const float* __restrict__ W1,
                      const unsigned short* __restrict__ bfrag,
                      float* __restrict__ mix, int E) {
    __shared__ unsigned int h_lds[4][64][32];   // packed bf16x2, XOR-swizzled

    int tid = threadIdx.x;
    int wave = tid >> 6;
    int lane = tid & 63;
    int r_ = lane & 15;
    int q  = lane >> 4;
    int qh = q >> 1;            // k parity within 2-k chunk
    int ul = (q & 1) * 8;       // u base for A-frag

    int ebase = blockIdx.x * 256 + wave * 64;

    // ---- phase 1: h[e][k] for this wave's 64 edges; lane owns k = lane ----
    float w1c[16];
    #pragma unroll
    for (int u = 0; u < 16; ++u)
        w1c[u] = W1[u * 64 + lane] * 0.25f;     // fold 1/sqrt(16)

    #pragma unroll 2
    for (int el = 0; el < 64; ++el) {
        int e = ebase + el; if (e >= E) e = E - 1;      // wave-uniform clamp
        const float* rp = radial + (size_t)e * 16;
        float z = 0.f;
        #pragma unroll
        for (int u = 0; u < 16; ++u) z = fmaf(rp[u], w1c[u], z);
        float h = z * __builtin_amdgcn_rcpf(1.0f + __expf(-z));   // silu
        float hn = __shfl_xor(h, 1);
        if (!(lane & 1)) {
            unsigned int w = cvt_pk_bf16(h, hn);        // (k=2t, k=2t+1)
            int t = lane >> 1;                          // 0..31
            h_lds[wave][el][t ^ (el & 31)] = w;
        }
    }

    // ---- phase 2: x for the wave's 4 M-tiles (f32, kept in regs) ----
    float x[4][8];
    #pragma unroll
    for (int m = 0; m < 4; ++m) {
        int e = ebase + m * 16 + r_; if (e >= E) e = E - 1;
        int src = ei[e];
        const float* xp = nf + (size_t)src * 16 + ul;
        float4 a = *(const float4*)xp;
        float4 b = *(const float4*)(xp + 4);
        x[m][0]=a.x; x[m][1]=a.y; x[m][2]=a.z; x[m][3]=a.w;
        x[m][4]=b.x; x[m][5]=b.y; x[m][6]=b.z; x[m][7]=b.w;
    }

    // ---- phase 3: K-loop, 32 steps of K=32 ----
    f32x4 acc[4][3];
    #pragma unroll
    for (int m = 0; m < 4; ++m)
        #pragma unroll
        for (int nt = 0; nt < 3; ++nt)
            acc[m][nt] = (f32x4){0.f, 0.f, 0.f, 0.f};

    for (int ks = 0; ks < 32; ++ks) {
        AFrag b[3];
        #pragma unroll
        for (int nt = 0; nt < 3; ++nt) {
            const uint4* p = (const uint4*)(bfrag + (size_t)(ks * 3 + nt) * 512 + lane * 8);
            uint4 t = *p;
            b[nt].u[0] = t.x; b[nt].u[1] = t.y; b[nt].u[2] = t.z; b[nt].u[3] = t.w;
        }
        #pragma unroll
        for (int m = 0; m < 4; ++m) {
            int el = m * 16 + r_;
            unsigned int hw = h_lds[wave][el][ks ^ (el & 31)];
            float h = __uint_as_float(qh ? (hw & 0xffff0000u) : (hw << 16));
            AFrag a;
            #pragma unroll
            for (int p2 = 0; p2 < 4; ++p2)
                a.u[p2] = cvt_pk_bf16(h * x[m][2 * p2], h * x[m][2 * p2 + 1]);
            #pragma unroll
            for (int nt = 0; nt < 3; ++nt)
                acc[m][nt] = __builtin_amdgcn_mfma_f32_16x16x32_bf16(a.v, b[nt].v, acc[m][nt], 0, 0, 0);
        }
    }

    // ---- epilogue: C layout col=lane&15, row=(lane>>4)*4+i ----
    #pragma unroll
    for (int m = 0; m < 4; ++m) {
        #pragma unroll
        for (int i = 0; i < 4; ++i) {
            int e = ebase + m * 16 + q * 4 + i;
            if (e < E) {
                float* mp = mix + (size_t)e * 48 + r_;
                mp[0]  = acc[m][0][i];
                mp[16] = acc[m][1][i];
                mp[32] = acc[m][2][i];
            }
        }
    }
}

// ------------------------------ gather -------------------------------------

__global__ __launch_bounds__(256)
void gather_kernel(const float* __restrict__ mix, const float* __restrict__ sh,
                   const int* __restrict__ eord, const int* __restrict__ offs,
                   const float* __restrict__ nf, const float* __restrict__ Wsi,
                   float* __restrict__ out, int N) {
    int node = blockIdx.x * 4 + (threadIdx.x >> 6);
    if (node >= N) return;
    int lane = threadIdx.x & 63;

    auto chmap = [](int c, int& mi, int& si) {
        if (c < 16)      { mi = c;                si = 0; }
        else if (c < 64) { int t = c - 16; mi = 16 + t / 3; si = 1 + t % 3; }
        else             { int t = c - 64; mi = 32 + t / 5; si = 4 + t % 5; }
    };
    int mi0, si0, mi1, si1, mi2 = 0, si2 = 0;
    chmap(lane, mi0, si0);
    chmap(lane + 64, mi1, si1);
    if (lane < 16) chmap(lane + 128, mi2, si2);

    float acc0 = 0.0f, acc1 = 0.0f, acc2 = 0.0f;
    int off = offs[node], end = offs[node + 1];
    for (int i = off; i < end; ++i) {
        int e = eord[i];
        const float* m = mix + (size_t)e * 48;
        const float* s = sh + (size_t)e * 9;
        acc0 = fmaf(m[mi0], s[si0], acc0);
        acc1 = fmaf(m[mi1], s[si1], acc1);
        if (lane < 16) acc2 = fmaf(m[mi2], s[si2], acc2);
    }

    if (lane < 16) {
        const float* xr = nf + (size_t)node * 16;
        float si = 0.0f;
        #pragma unroll
        for (int u = 0; u < 16; ++u)
            si = fmaf(xr[u], Wsi[u * 16 + lane], si);
        acc0 = fmaf(si, 0.25f, acc0);
    }

    float* orow = out + (size_t)node * 144;
    orow[lane] = acc0;
    orow[lane + 64] = acc1;
    if (lane < 16) orow[lane + 128] = acc2;
}

// ------------------------- fallback (atomic path) --------------------------

__global__ __launch_bounds__(256)
void si_init_kernel(const float* __restrict__ nf, const float* __restrict__ Wsi,
                    float* __restrict__ out, int N) {
    int t = blockIdx.x * blockDim.x + threadIdx.x;
    int total = N * 144;
    if (t >= total) return;
    int n = t / 144;
    int c = t - n * 144;
    float val = 0.0f;
    if (c < 16) {
        const float* xr = nf + n * 16;
        #pragma unroll
        for (int u = 0; u < 16; ++u)
            val = fmaf(xr[u], Wsi[u * 16 + c], val);
        val *= 0.25f;
    }
    out[t] = val;
}

__global__ __launch_bounds__(256)
void edge_kernel_atomic(const float* __restrict__ nf, const int* __restrict__ ei,
                        const float* __restrict__ sh, const float* __restrict__ radial,
                        const float* __restrict__ W1, const float* __restrict__ W2,
                        float* __restrict__ out, int E) {
    int e = blockIdx.x * blockDim.x + threadIdx.x;
    if (e >= E) return;
    int src = ei[e];
    int dst = ei[E + e];
    float r[16], x[16];
    #pragma unroll
    for (int u = 0; u < 16; ++u) r[u] = radial[e * 16 + u] * 0.25f;
    #pragma unroll
    for (int u = 0; u < 16; ++u) x[u] = nf[src * 16 + u] * 0.03125f;
    float acc[48];
    #pragma unroll
    for (int j = 0; j < 48; ++j) acc[j] = 0.0f;
    for (int k = 0; k < 64; ++k) {
        float z = 0.0f;
        #pragma unroll
        for (int u = 0; u < 16; ++u) z = fmaf(r[u], W1[u * 64 + k], z);
        float hk = z / (1.0f + __expf(-z));
        const float* w2k = W2 + k * 768;
        #pragma unroll 4
        for (int u = 0; u < 16; ++u) {
            float p = hk * x[u];
            const float* w = w2k + u * 16;
            #pragma unroll
            for (int l = 0; l < 3; ++l)
                #pragma unroll
                for (int v = 0; v < 16; ++v)
                    acc[l * 16 + v] = fmaf(p, w[l * 256 + v], acc[l * 16 + v]);
        }
    }
    const float* she = sh + e * 9;
    float* orow = out + (long)dst * 144;
    #pragma unroll
    for (int v = 0; v < 16; ++v) atomicAdd(&orow[v], acc[v] * she[0]);
    #pragma unroll
    for (int v = 0; v < 16; ++v)
        for (int m = 0; m < 3; ++m)
            atomicAdd(&orow[16 + v * 3 + m], acc[16 + v] * she[1 + m]);
    #pragma unroll
    for (int v = 0; v < 16; ++v)
        for (int m = 0; m < 5; ++m)
            atomicAdd(&orow[64 + v * 5 + m], acc[32 + v] * she[4 + m]);
}

// ---------------------------------------------------------------------------

extern "C" void kernel_launch(void* const* d_in, const int* in_sizes, int n_in,
                              void* d_out, int out_size, void* d_ws, size_t ws_size,
                              hipStream_t stream) {
    const float* nf     = (const float*)d_in[0];
    const int*   ei     = (const int*)  d_in[1];
    const float* sh     = (const float*)d_in[2];
    const float* radial = (const float*)d_in[3];
    const float* W1     = (const float*)d_in[4];
    const float* W2     = (const float*)d_in[5];
    const float* Wsi    = (const float*)d_in[6];
    float* out = (float*)d_out;

    const int N = in_sizes[0] / 16;
    const int E = in_sizes[1] / 2;

    size_t mix_bytes  = (size_t)E * 48 * sizeof(float);
    size_t offs_bytes = (size_t)(N + 1) * sizeof(int);
    size_t curs_bytes = (size_t)N * sizeof(int);
    size_t eord_bytes = (size_t)E * sizeof(int);
    size_t bfrag_off  = (mix_bytes + offs_bytes + curs_bytes + eord_bytes + 15) & ~(size_t)15;
    size_t bfrag_bytes = 96 * 512 * sizeof(unsigned short);   // 96 KB
    size_t need = bfrag_off + bfrag_bytes;

    if (ws_size < need) {
        int total = N * 144;
        hipLaunchKernelGGL(si_init_kernel, dim3((total + 255) / 256), dim3(256), 0, stream,
                           nf, Wsi, out, N);
        hipLaunchKernelGGL(edge_kernel_atomic, dim3((E + 255) / 256), dim3(256), 0, stream,
                           nf, ei, sh, radial, W1, W2, out, E);
        return;
    }

    float* mix  = (float*)d_ws;
    int*   offs = (int*)((char*)d_ws + mix_bytes);
    int*   curs = (int*)((char*)d_ws + mix_bytes + offs_bytes);
    int*   eord = (int*)((char*)d_ws + mix_bytes + offs_bytes + curs_bytes);
    unsigned short* bfrag = (unsigned short*)((char*)d_ws + bfrag_off);

    hipMemsetAsync(offs, 0, offs_bytes + curs_bytes, stream);

    int eb = (E + 255) / 256;
    hipLaunchKernelGGL(bfrag_prep_kernel, dim3(192), dim3(256), 0, stream, W2, bfrag);
    hipLaunchKernelGGL(hist_kernel, dim3(eb), dim3(256), 0, stream, ei, offs, E);
    hipLaunchKernelGGL(scan_kernel, dim3(1), dim3(1024), 0, stream, offs, N + 1);
    hipLaunchKernelGGL(scatter_kernel, dim3(eb), dim3(256), 0, stream, ei, offs, curs, eord, E);

    int mblocks = (E + 255) / 256;   // 4 waves x 64 edges per block
    hipLaunchKernelGGL(edge_mfma_kernel, dim3(mblocks), dim3(256), 0, stream,
                       nf, ei, radial, W1, bfrag, mix, E);
    hipLaunchKernelGGL(gather_kernel, dim3((N + 3) / 4), dim3(256), 0, stream,
                       mix, sh, eord, offs, nf, Wsi, out, N);
}